// Round 1
// baseline (321.304 us; speedup 1.0000x reference)
//
#include <hip/hip_runtime.h>
#include <math.h>

#define B_ 128
#define N_ 100
#define E_ 100
#define D_ 64
#define LALPHA 0.2f
#define NEGV -9e15f

__device__ inline float wave_max(float v) {
    #pragma unroll
    for (int off = 32; off; off >>= 1) v = fmaxf(v, __shfl_xor(v, off));
    return v;
}
__device__ inline float wave_sum(float v) {
    #pragma unroll
    for (int off = 32; off; off >>= 1) v += __shfl_xor(v, off);
    return v;
}

// node -> edge attention: computes edge[b,e,:] for one (b,e) per block.
// edge_cluster[b,e,d] = sum_n (H>0) h[n,d]   (computed in-block)
// s[n] = leaky(sum_d ec[d]*a_{k-1}[d]*h[n,d]) if k=H[b,n,e]>0 else NEG
// alpha = softmax_n(s); edge[b,e,d] = sum_n alpha[n] h[n,d]
__global__ __launch_bounds__(256) void k_n2e(
    const float* __restrict__ h,   // (B,N,D)
    const float* __restrict__ Hm,  // (B,N,E)
    const float* __restrict__ a0,
    const float* __restrict__ a1,
    const float* __restrict__ a2,
    float* __restrict__ edge)      // (B,E,D)
{
    __shared__ float sh_h[N_ * 65];
    __shared__ int   sh_k[N_];
    __shared__ float sh_eck[3][D_];
    __shared__ float sh_part[4][D_];
    __shared__ float sh_s[N_];
    __shared__ float sh_red[4];

    const int e = blockIdx.x, b = blockIdx.y;
    const int tid = threadIdx.x;

    // stage h tile (coalesced float4 global loads, scalar LDS writes)
    for (int i = tid * 4; i < N_ * D_; i += 256 * 4) {
        const float4 v = *reinterpret_cast<const float4*>(&h[b * N_ * D_ + i]);
        const int n = i >> 6, d = i & 63;
        float* r = &sh_h[n * 65 + d];
        r[0] = v.x; r[1] = v.y; r[2] = v.z; r[3] = v.w;
    }
    if (tid < N_) sh_k[tid] = (int)Hm[(b * N_ + tid) * E_ + e];
    __syncthreads();

    // edge_cluster (masked column sum over n), split in 4 n-quarters
    {
        const int q = tid >> 6, d = tid & 63;
        float p = 0.f;
        for (int n = q * 25; n < q * 25 + 25; ++n)
            p += (sh_k[n] > 0) ? sh_h[n * 65 + d] : 0.f;
        sh_part[q][d] = p;
    }
    __syncthreads();
    if (tid < D_) {
        const float ec = sh_part[0][tid] + sh_part[1][tid] + sh_part[2][tid] + sh_part[3][tid];
        sh_eck[0][tid] = ec * a0[tid];
        sh_eck[1][tid] = ec * a1[tid];
        sh_eck[2][tid] = ec * a2[tid];
    }
    __syncthreads();

    // scores: two threads per n, each 32-elem partial dot
    {
        const int n = tid >> 1, half = tid & 1;
        float p = 0.f;
        int k = 0;
        if (n < N_) {
            k = sh_k[n];
            if (k > 0) {
                const float* ek = sh_eck[k - 1];
                const float* hr = &sh_h[n * 65 + half * 32];
                #pragma unroll
                for (int dd = 0; dd < 32; ++dd) p += ek[half * 32 + dd] * hr[dd];
            }
        }
        p += __shfl_xor(p, 1);
        if (n < N_ && half == 0) {
            float s;
            if (k > 0) s = (p >= 0.f) ? p : LALPHA * p;
            else       s = NEGV;
            sh_s[n] = s;
        }
    }
    __syncthreads();

    // softmax over n (max then sum; fold 1/tot into final accumulation)
    float v = (tid < N_) ? sh_s[tid] : -INFINITY;
    v = wave_max(v);
    if ((tid & 63) == 0) sh_red[tid >> 6] = v;
    __syncthreads();
    const float mx = fmaxf(fmaxf(sh_red[0], sh_red[1]), fmaxf(sh_red[2], sh_red[3]));
    float ex = 0.f;
    if (tid < N_) ex = __expf(sh_s[tid] - mx);
    __syncthreads();
    if (tid < N_) sh_s[tid] = ex;
    float sv = wave_sum(ex);
    if ((tid & 63) == 0) sh_red[tid >> 6] = sv;
    __syncthreads();
    const float tot = sh_red[0] + sh_red[1] + sh_red[2] + sh_red[3];
    const float inv = 1.0f / tot;

    // edge[d] = (sum_n ex[n] h[n,d]) * inv
    {
        const int q = tid >> 6, d = tid & 63;
        float p = 0.f;
        for (int n = q * 25; n < q * 25 + 25; ++n)
            p += sh_s[n] * sh_h[n * 65 + d];
        sh_part[q][d] = p;
    }
    __syncthreads();
    if (tid < D_) {
        const float r = (sh_part[0][tid] + sh_part[1][tid] + sh_part[2][tid] + sh_part[3][tid]) * inv;
        edge[(b * E_ + e) * D_ + tid] = r;
    }
}

// edge -> node attention: one (b,n) per block.
// ht[d] = h[b,n,d] + s_c[b,d]
// s[e] = leaky(sum_d edge[b,e,d]*ht[d]*a_{k-1}[d]) if k=H[b,n,e]>0 else NEG
// alpha = softmax_e(s); out[b,n,d] (+)= sum_e alpha[e] edge[b,e,d]
template<bool WRITE_NEXT, bool ACC>
__global__ __launch_bounds__(256) void k_e2n(
    const float* __restrict__ h,    // (B,N,D) current layer h_emb
    const float* __restrict__ s_c,  // (B,1,D)
    const float* __restrict__ Hm,   // (B,N,E)
    const float* __restrict__ a0,
    const float* __restrict__ a1,
    const float* __restrict__ a2,
    const float* __restrict__ edge, // (B,E,D)
    float* __restrict__ h_next,     // (B,N,D) or null
    float* __restrict__ out)        // (B,N,D)
{
    __shared__ float sh_e[E_ * 65];
    __shared__ int   sh_k[E_];
    __shared__ float sh_htk[3][D_];
    __shared__ float sh_part[4][D_];
    __shared__ float sh_s[E_];
    __shared__ float sh_red[4];

    const int n = blockIdx.x, b = blockIdx.y;
    const int tid = threadIdx.x;

    for (int i = tid * 4; i < E_ * D_; i += 256 * 4) {
        const float4 v = *reinterpret_cast<const float4*>(&edge[b * E_ * D_ + i]);
        const int ee = i >> 6, d = i & 63;
        float* r = &sh_e[ee * 65 + d];
        r[0] = v.x; r[1] = v.y; r[2] = v.z; r[3] = v.w;
    }
    if (tid < E_) sh_k[tid] = (int)Hm[(b * N_ + n) * E_ + tid];  // coalesced
    if (tid < D_) {
        const float ht = h[(b * N_ + n) * D_ + tid] + s_c[b * D_ + tid];
        sh_htk[0][tid] = ht * a0[tid];
        sh_htk[1][tid] = ht * a1[tid];
        sh_htk[2][tid] = ht * a2[tid];
    }
    __syncthreads();

    // scores over e: two threads per e
    {
        const int e = tid >> 1, half = tid & 1;
        float p = 0.f;
        int k = 0;
        if (e < E_) {
            k = sh_k[e];
            if (k > 0) {
                const float* hk = sh_htk[k - 1];
                const float* er = &sh_e[e * 65 + half * 32];
                #pragma unroll
                for (int dd = 0; dd < 32; ++dd) p += hk[half * 32 + dd] * er[dd];
            }
        }
        p += __shfl_xor(p, 1);
        if (e < E_ && half == 0) {
            float s;
            if (k > 0) s = (p >= 0.f) ? p : LALPHA * p;
            else       s = NEGV;
            sh_s[e] = s;
        }
    }
    __syncthreads();

    float v = (tid < E_) ? sh_s[tid] : -INFINITY;
    v = wave_max(v);
    if ((tid & 63) == 0) sh_red[tid >> 6] = v;
    __syncthreads();
    const float mx = fmaxf(fmaxf(sh_red[0], sh_red[1]), fmaxf(sh_red[2], sh_red[3]));
    float ex = 0.f;
    if (tid < E_) ex = __expf(sh_s[tid] - mx);
    __syncthreads();
    if (tid < E_) sh_s[tid] = ex;
    float sv = wave_sum(ex);
    if ((tid & 63) == 0) sh_red[tid >> 6] = sv;
    __syncthreads();
    const float tot = sh_red[0] + sh_red[1] + sh_red[2] + sh_red[3];
    const float inv = 1.0f / tot;

    {
        const int q = tid >> 6, d = tid & 63;
        float p = 0.f;
        for (int e = q * 25; e < q * 25 + 25; ++e)
            p += sh_s[e] * sh_e[e * 65 + d];
        sh_part[q][d] = p;
    }
    __syncthreads();
    if (tid < D_) {
        const float r = (sh_part[0][tid] + sh_part[1][tid] + sh_part[2][tid] + sh_part[3][tid]) * inv;
        const int idx = (b * N_ + n) * D_ + tid;
        if (WRITE_NEXT) h_next[idx] = r;
        if (ACC) out[idx] += r; else out[idx] = r;
    }
}

extern "C" void kernel_launch(void* const* d_in, const int* in_sizes, int n_in,
                              void* d_out, int out_size, void* d_ws, size_t ws_size,
                              hipStream_t stream) {
    const float* hidden = (const float*)d_in[0];
    const float* Hm     = (const float*)d_in[1];
    const float* s_c    = (const float*)d_in[2];
    const float* a10    = (const float*)d_in[3];
    const float* a11    = (const float*)d_in[4];
    const float* a12    = (const float*)d_in[5];
    const float* a20    = (const float*)d_in[6];
    const float* a21    = (const float*)d_in[7];
    const float* a22    = (const float*)d_in[8];
    float* out = (float*)d_out;

    float* edge  = (float*)d_ws;              // B*E*D floats
    float* hnext = edge + (size_t)B_ * E_ * D_; // B*N*D floats

    const dim3 gE(E_, B_), gN(N_, B_);

    // layer 1
    k_n2e<<<gE, 256, 0, stream>>>(hidden, Hm, a10, a11, a12, edge);
    k_e2n<true, false><<<gN, 256, 0, stream>>>(hidden, s_c, Hm, a20, a21, a22, edge, hnext, out);
    // layer 2
    k_n2e<<<gE, 256, 0, stream>>>(hnext, Hm, a10, a11, a12, edge);
    k_e2n<false, true><<<gN, 256, 0, stream>>>(hnext, s_c, Hm, a20, a21, a22, edge, nullptr, out);
}